// Round 22
// baseline (73.977 us; speedup 1.0000x reference)
//
#include <hip/hip_runtime.h>
#include <hip/hip_bf16.h>

#define BATCH   16384
#define INF     512
#define OUTF    512
#define THREADS 768

using f32x4  = __attribute__((ext_vector_type(4))) float;
using bf16x8 = __attribute__((ext_vector_type(8))) short;

__device__ __forceinline__ short f2bf(float f) {
    unsigned int u = __builtin_bit_cast(unsigned int, f);
    u += 0x7fff + ((u >> 16) & 1);          // round-to-nearest-even
    return (short)(u >> 16);
}

__device__ __forceinline__ unsigned cvtpk(float lo, float hi) {
    unsigned r;
    asm("v_cvt_pk_bf16_f32 %0, %1, %2" : "=v"(r) : "v"(lo), "v"(hi));
    return r;
}

// closed-form silu + 6 basis planes for 8 x (cvt_pk packing, RNE = f2bf)
__device__ __forceinline__ void bases8_pk(const float* xv, uint4* o) {
    float sv[8], n0[8], n1[8], n2[8], n3[8];
    int sel[8];
    #pragma unroll
    for (int e = 0; e < 8; ++e) {
        float x = xv[e];
        sv[e] = x * __builtin_amdgcn_rcpf(1.0f + __expf(-x));
        const float k2 = 2.0f * 0.4f - 1.0f;   // ref-exact f32 knots
        const float k3 = 3.0f * 0.4f - 1.0f;
        const float k4 = 4.0f * 0.4f - 1.0f;
        sel[e] = (int)(x >= k3) + (int)(x >= k4);
        float gL = (sel[e] == 0) ? k2 : (sel[e] == 1) ? k3 : k4;
        float tt = (x - gL) * 2.5f;
        float u  = 1.0f - tt;
        float t2 = tt * tt;
        n0[e] = u * u * u * (1.0f / 6.0f);
        n1[e] = (0.5f * tt - 1.0f) * t2 + (2.0f / 3.0f);
        n2[e] = ((-0.5f * tt + 0.5f) * tt + 0.5f) * tt + (1.0f / 6.0f);
        n3[e] = tt * t2 * (1.0f / 6.0f);
    }
    o[0] = (uint4){cvtpk(sv[0], sv[1]), cvtpk(sv[2], sv[3]),
                   cvtpk(sv[4], sv[5]), cvtpk(sv[6], sv[7])};
    #pragma unroll
    for (int sp = 0; sp < 6; ++sp) {
        float v[8];
        #pragma unroll
        for (int e = 0; e < 8; ++e)
            v[e] = (sp == sel[e])     ? n0[e] :
                   (sp == sel[e] + 1) ? n1[e] :
                   (sp == sel[e] + 2) ? n2[e] :
                   (sp == sel[e] + 3) ? n3[e] : 0.0f;
        o[1 + sp] = (uint4){cvtpk(v[0], v[1]), cvtpk(v[2], v[3]),
                            cvtpk(v[4], v[5]), cvtpk(v[6], v[7])};
    }
}

// ---- prep W5 (R13-R16 layout): fragment-ordered, 8 col-groups of 64 ---------
// Wt[g][sidx=ic*7+q][ni 4][lane 64][8 shorts]; lane=kc*16+r holds
// W[o = g*64+ni*16+r][plane q][i = ic*32+kc*8 ..+8]
__global__ void prep_w5(const float* __restrict__ bw, const float* __restrict__ sw,
                        const float* __restrict__ ss, short* __restrict__ Wt) {
    int idx = blockIdx.x * blockDim.x + threadIdx.x;   // (o:512) x (q:7) x (c:64)
    if (idx >= OUTF * 7 * 64) return;
    int c = idx & 63;
    int q = (idx >> 6) % 7;
    int o = idx / (7 * 64);
    int ic = c >> 2, kc = c & 3;
    int i0 = c * 8;
    int g  = o >> 6;
    int ni = (o >> 4) & 3, r = o & 15;
    int lane = kc * 16 + r;
    size_t dst = ((((size_t)g * 112 + (ic * 7 + q)) * 4 + ni) * 64 + lane) * 8;
    short v[8];
    if (q == 0) {
        #pragma unroll
        for (int e = 0; e < 8; ++e) v[e] = f2bf(bw[(size_t)o * INF + i0 + e]);
    } else {
        #pragma unroll
        for (int e = 0; e < 8; ++e) {
            size_t ii = (size_t)o * INF + i0 + e;
            v[e] = f2bf(sw[ii * 8 + q + 1] * ss[ii]);
        }
    }
    *(bf16x8*)&Wt[dst] = *(bf16x8*)v;
}

// ---- fused v14 = kan_pc2 MINUS s_setprio ------------------------------------
// Theory: with 2 consumers + 1 producer per SIMD, setprio(1) around each
// 310-cyc MFMA cluster starves the sibling consumer's load phase -> the two
// consumers' MFMA clusters alternate instead of overlap (wall = 2x cluster
// = 1240 cyc/step, matching measured 1226). Default round-robin arbitration
// lets B's loads issue during A's MFMA. Everything else identical to the
// reproduced 65.7 us kernel.
#define BARRIER() asm volatile("s_barrier" ::: "memory")
#define LGKM0()   asm volatile("s_waitcnt lgkmcnt(0)" ::: "memory")
#define MFMA1(d, a, b) d = __builtin_amdgcn_mfma_f32_16x16x32_bf16(a, b, d, 0, 0, 0)

#define BLD(PAR, NS) do { \
    breg[PAR][0] = *(const bf16x8*)(pBw + (size_t)(NS) * 2048); \
    breg[PAR][1] = *(const bf16x8*)(pBw + (size_t)(NS) * 2048 + 512); \
    breg[PAR][2] = *(const bf16x8*)(pBw + (size_t)(NS) * 2048 + 1024); \
    breg[PAR][3] = *(const bf16x8*)(pBw + (size_t)(NS) * 2048 + 1536); \
} while (0)

#define CSTEP2(IC, Q, PAR, BR, AFC, AFN) do { \
    int sidx_ = (IC) * 7 + (Q); \
    int ns_ = (sidx_ < 111) ? sidx_ + 1 : 111; \
    BLD((PAR) ^ 1, ns_); \
    if ((Q) < 6) { \
        _Pragma("unroll") \
        for (int mi = 0; mi < 4; ++mi) \
            AFN[mi] = *(const bf16x8*)(L + (BR) + ((Q) + 1) * 4096 + mi * 1024 + ard); \
    } \
    _Pragma("unroll") \
    for (int mi = 0; mi < 4; ++mi) { \
        MFMA1(acc[mi][0], AFC[mi], breg[PAR][0]); \
        MFMA1(acc[mi][1], AFC[mi], breg[PAR][1]); \
        MFMA1(acc[mi][2], AFC[mi], breg[PAR][2]); \
        MFMA1(acc[mi][3], AFC[mi], breg[PAR][3]); \
    } \
} while (0)

#define CBLOCK2(IC, P0, BR) do { \
    _Pragma("unroll") \
    for (int mi = 0; mi < 4; ++mi) \
        afE[mi] = *(const bf16x8*)(L + (BR) + mi * 1024 + ard); \
    CSTEP2(IC, 0, ((P0) + 0) & 1, BR, afE, afO); \
    CSTEP2(IC, 1, ((P0) + 1) & 1, BR, afO, afE); \
    CSTEP2(IC, 2, ((P0) + 2) & 1, BR, afE, afO); \
    CSTEP2(IC, 3, ((P0) + 3) & 1, BR, afO, afE); \
    CSTEP2(IC, 4, ((P0) + 4) & 1, BR, afE, afO); \
    CSTEP2(IC, 5, ((P0) + 5) & 1, BR, afO, afE); \
    CSTEP2(IC, 6, ((P0) + 6) & 1, BR, afE, afO); \
} while (0)

#define PROD(TGT, BW) do { \
    float4 xa_ = *(const float4*)(gxp + (TGT) * 32); \
    float4 xb_ = *(const float4*)(gxp + (TGT) * 32 + 4); \
    float xv_[8] = {xa_.x, xa_.y, xa_.z, xa_.w, xb_.x, xb_.y, xb_.z, xb_.w}; \
    uint4 o_[7]; \
    bases8_pk(xv_, o_); \
    _Pragma("unroll") \
    for (int qq = 0; qq < 7; ++qq) \
        *(uint4*)(L + (BW) + qq * 4096 + awr) = o_[qq]; \
} while (0)

__global__ __launch_bounds__(THREADS, 1) void kan_pc5(
        const float* __restrict__ x, const short* __restrict__ Wt,
        float* __restrict__ C) {
    __shared__ short lds[28672];                 // 56 KB: 2 bufs x 7 x 64 x 64B
    char* L = (char*)lds;

    int bm = blockIdx.x;
    int t = threadIdx.x, wid = t >> 6, lane = t & 63;
    int r = lane & 15, kc = lane >> 4;

    // consumer addressing (verified): A read swizzle + B frag base
    unsigned ard = (unsigned)(r * 64 + (((kc ^ ((r >> 1) & 3)) & 3) * 16));
    const short* pBw = Wt + (size_t)(wid & 7) * 112 * 2048 + (size_t)lane * 8;

    // producer addressing: pw 0..3; row = pw*16 + lane>>2, chunk = lane&3
    int pw = (wid - 8) & 3;
    int prow = pw * 16 + (lane >> 2);
    int pch = lane & 3;
    const float* gxp = x + ((size_t)bm * 64 + prow) * INF + pch * 8;
    unsigned awr = (unsigned)(prow * 64 + (((pch ^ ((prow >> 1) & 3)) & 3) * 16));

    f32x4 acc[4][4] = {};
    bf16x8 breg[2][4], afE[4], afO[4];

    // prologue: producers build block 0 -> buf0; consumers preload B(sidx 0)
    if (wid >= 8) { PROD(0, 0); }
    else          { BLD(0, 0); }
    LGKM0();
    BARRIER();

    for (int bb = 0; bb < 16; bb += 2) {
        if (wid < 8) { CBLOCK2(bb, 0, 0); }
        else         { PROD(bb + 1, 28672); }
        LGKM0();
        BARRIER();
        if (wid < 8) { CBLOCK2(bb + 1, 1, 28672); }
        else         { if (bb + 2 < 16) PROD(bb + 2, 0); }
        LGKM0();
        BARRIER();
    }

    // epilogue (consumers only): D row = (lane>>4)*4 + j, col = lane&15
    if (wid < 8) {
        int cr = (lane >> 4) * 4;
        int cc = lane & 15;
        #pragma unroll
        for (int mi = 0; mi < 4; ++mi) {
            #pragma unroll
            for (int ni = 0; ni < 4; ++ni) {
                size_t row = (size_t)bm * 64 + mi * 16 + cr;
                int col = wid * 64 + ni * 16 + cc;
                #pragma unroll
                for (int j = 0; j < 4; ++j)
                    C[(row + j) * OUTF + col] = acc[mi][ni][j];
            }
        }
    }
}

extern "C" void kernel_launch(void* const* d_in, const int* in_sizes, int n_in,
                              void* d_out, int out_size, void* d_ws, size_t ws_size,
                              hipStream_t stream) {
    const float* x  = (const float*)d_in[0];
    const float* bw = (const float*)d_in[1];
    const float* sw = (const float*)d_in[2];
    const float* ss = (const float*)d_in[3];
    float* out = (float*)d_out;
    short* Wbuf = (short*)d_ws;                          // 3.67 MB

    prep_w5<<<(OUTF * 7 * 64 + 255) / 256, 256, 0, stream>>>(bw, sw, ss, Wbuf);
    kan_pc5<<<BATCH / 64, THREADS, 0, stream>>>(x, Wbuf, out);
}

// Round 23
// 65.429 us; speedup vs baseline: 1.1306x; 1.1306x over previous
//
#include <hip/hip_runtime.h>
#include <hip/hip_bf16.h>

#define BATCH   16384
#define INF     512
#define OUTF    512
#define THREADS 768

using f32x4  = __attribute__((ext_vector_type(4))) float;
using bf16x8 = __attribute__((ext_vector_type(8))) short;

__device__ __forceinline__ short f2bf(float f) {
    unsigned int u = __builtin_bit_cast(unsigned int, f);
    u += 0x7fff + ((u >> 16) & 1);          // round-to-nearest-even
    return (short)(u >> 16);
}

__device__ __forceinline__ unsigned cvtpk(float lo, float hi) {
    unsigned r;
    asm("v_cvt_pk_bf16_f32 %0, %1, %2" : "=v"(r) : "v"(lo), "v"(hi));
    return r;
}

// closed-form silu + 6 basis planes for 8 x (cvt_pk packing, RNE = f2bf)
__device__ __forceinline__ void bases8_pk(const float* xv, uint4* o) {
    float sv[8], n0[8], n1[8], n2[8], n3[8];
    int sel[8];
    #pragma unroll
    for (int e = 0; e < 8; ++e) {
        float x = xv[e];
        sv[e] = x * __builtin_amdgcn_rcpf(1.0f + __expf(-x));
        const float k2 = 2.0f * 0.4f - 1.0f;   // ref-exact f32 knots
        const float k3 = 3.0f * 0.4f - 1.0f;
        const float k4 = 4.0f * 0.4f - 1.0f;
        sel[e] = (int)(x >= k3) + (int)(x >= k4);
        float gL = (sel[e] == 0) ? k2 : (sel[e] == 1) ? k3 : k4;
        float tt = (x - gL) * 2.5f;
        float u  = 1.0f - tt;
        float t2 = tt * tt;
        n0[e] = u * u * u * (1.0f / 6.0f);
        n1[e] = (0.5f * tt - 1.0f) * t2 + (2.0f / 3.0f);
        n2[e] = ((-0.5f * tt + 0.5f) * tt + 0.5f) * tt + (1.0f / 6.0f);
        n3[e] = tt * t2 * (1.0f / 6.0f);
    }
    o[0] = (uint4){cvtpk(sv[0], sv[1]), cvtpk(sv[2], sv[3]),
                   cvtpk(sv[4], sv[5]), cvtpk(sv[6], sv[7])};
    #pragma unroll
    for (int sp = 0; sp < 6; ++sp) {
        float v[8];
        #pragma unroll
        for (int e = 0; e < 8; ++e)
            v[e] = (sp == sel[e])     ? n0[e] :
                   (sp == sel[e] + 1) ? n1[e] :
                   (sp == sel[e] + 2) ? n2[e] :
                   (sp == sel[e] + 3) ? n3[e] : 0.0f;
        o[1 + sp] = (uint4){cvtpk(v[0], v[1]), cvtpk(v[2], v[3]),
                            cvtpk(v[4], v[5]), cvtpk(v[6], v[7])};
    }
}

// ---- prep W5: fragment-ordered, 8 col-groups of 64 --------------------------
// Wt[g][sidx=ic*7+q][ni 4][lane 64][8 shorts]; lane=kc*16+r holds
// W[o = g*64+ni*16+r][plane q][i = ic*32+kc*8 ..+8]
__global__ void prep_w5(const float* __restrict__ bw, const float* __restrict__ sw,
                        const float* __restrict__ ss, short* __restrict__ Wt) {
    int idx = blockIdx.x * blockDim.x + threadIdx.x;   // (o:512) x (q:7) x (c:64)
    if (idx >= OUTF * 7 * 64) return;
    int c = idx & 63;
    int q = (idx >> 6) % 7;
    int o = idx / (7 * 64);
    int ic = c >> 2, kc = c & 3;
    int i0 = c * 8;
    int g  = o >> 6;
    int ni = (o >> 4) & 3, r = o & 15;
    int lane = kc * 16 + r;
    size_t dst = ((((size_t)g * 112 + (ic * 7 + q)) * 4 + ni) * 64 + lane) * 8;
    short v[8];
    if (q == 0) {
        #pragma unroll
        for (int e = 0; e < 8; ++e) v[e] = f2bf(bw[(size_t)o * INF + i0 + e]);
    } else {
        #pragma unroll
        for (int e = 0; e < 8; ++e) {
            size_t ii = (size_t)o * INF + i0 + e;
            v[e] = f2bf(sw[ii * 8 + q + 1] * ss[ii]);
        }
    }
    *(bf16x8*)&Wt[dst] = *(bf16x8*)v;
}

// ---- FINAL: producer/consumer + A-frag pipeline + setprio (65.5 us) ----------
// 256 WGs x 768 thr = 12 waves: wid 0..7 consumers (64 rows x 64 cols each,
// 16 MFMA/step, B reg ping-pong from fragment-ordered Wt), wid 8..11 producers
// (x -> bases -> A planes in LDS). A dbuf: [2][7][64 rows][64 B] = 56 KB,
// measured-0-conflict swizzle. Producers build block b+1 into the idle buffer
// while consumers run 7 steps on block b. setprio(1) around MFMA clusters is
// A/B-verified +20% here (R21: removal -> 69.4 us). 3 waves/SIMD is the
// register-file cap for this accumulator footprint (R17/R19: both escapes
// measured fatal - no co-residency at 144 regs, spills at 85).
#define BARRIER() asm volatile("s_barrier" ::: "memory")
#define LGKM0()   asm volatile("s_waitcnt lgkmcnt(0)" ::: "memory")
#define MFMA1(d, a, b) d = __builtin_amdgcn_mfma_f32_16x16x32_bf16(a, b, d, 0, 0, 0)

#define BLD(PAR, NS) do { \
    breg[PAR][0] = *(const bf16x8*)(pBw + (size_t)(NS) * 2048); \
    breg[PAR][1] = *(const bf16x8*)(pBw + (size_t)(NS) * 2048 + 512); \
    breg[PAR][2] = *(const bf16x8*)(pBw + (size_t)(NS) * 2048 + 1024); \
    breg[PAR][3] = *(const bf16x8*)(pBw + (size_t)(NS) * 2048 + 1536); \
} while (0)

#define CSTEP2(IC, Q, PAR, BR, AFC, AFN) do { \
    int sidx_ = (IC) * 7 + (Q); \
    int ns_ = (sidx_ < 111) ? sidx_ + 1 : 111; \
    BLD((PAR) ^ 1, ns_); \
    if ((Q) < 6) { \
        _Pragma("unroll") \
        for (int mi = 0; mi < 4; ++mi) \
            AFN[mi] = *(const bf16x8*)(L + (BR) + ((Q) + 1) * 4096 + mi * 1024 + ard); \
    } \
    __builtin_amdgcn_s_setprio(1); \
    _Pragma("unroll") \
    for (int mi = 0; mi < 4; ++mi) { \
        MFMA1(acc[mi][0], AFC[mi], breg[PAR][0]); \
        MFMA1(acc[mi][1], AFC[mi], breg[PAR][1]); \
        MFMA1(acc[mi][2], AFC[mi], breg[PAR][2]); \
        MFMA1(acc[mi][3], AFC[mi], breg[PAR][3]); \
    } \
    __builtin_amdgcn_s_setprio(0); \
} while (0)

#define CBLOCK2(IC, P0, BR) do { \
    _Pragma("unroll") \
    for (int mi = 0; mi < 4; ++mi) \
        afE[mi] = *(const bf16x8*)(L + (BR) + mi * 1024 + ard); \
    CSTEP2(IC, 0, ((P0) + 0) & 1, BR, afE, afO); \
    CSTEP2(IC, 1, ((P0) + 1) & 1, BR, afO, afE); \
    CSTEP2(IC, 2, ((P0) + 2) & 1, BR, afE, afO); \
    CSTEP2(IC, 3, ((P0) + 3) & 1, BR, afO, afE); \
    CSTEP2(IC, 4, ((P0) + 4) & 1, BR, afE, afO); \
    CSTEP2(IC, 5, ((P0) + 5) & 1, BR, afO, afE); \
    CSTEP2(IC, 6, ((P0) + 6) & 1, BR, afE, afO); \
} while (0)

#define PROD(TGT, BW) do { \
    float4 xa_ = *(const float4*)(gxp + (TGT) * 32); \
    float4 xb_ = *(const float4*)(gxp + (TGT) * 32 + 4); \
    float xv_[8] = {xa_.x, xa_.y, xa_.z, xa_.w, xb_.x, xb_.y, xb_.z, xb_.w}; \
    uint4 o_[7]; \
    bases8_pk(xv_, o_); \
    _Pragma("unroll") \
    for (int qq = 0; qq < 7; ++qq) \
        *(uint4*)(L + (BW) + qq * 4096 + awr) = o_[qq]; \
} while (0)

__global__ __launch_bounds__(THREADS, 1) void kan_pc2(
        const float* __restrict__ x, const short* __restrict__ Wt,
        float* __restrict__ C) {
    __shared__ short lds[28672];                 // 56 KB: 2 bufs x 7 x 64 x 64B
    char* L = (char*)lds;

    int bm = blockIdx.x;
    int t = threadIdx.x, wid = t >> 6, lane = t & 63;
    int r = lane & 15, kc = lane >> 4;

    // consumer addressing (verified): A read swizzle + B frag base
    unsigned ard = (unsigned)(r * 64 + (((kc ^ ((r >> 1) & 3)) & 3) * 16));
    const short* pBw = Wt + (size_t)(wid & 7) * 112 * 2048 + (size_t)lane * 8;

    // producer addressing: pw 0..3; row = pw*16 + lane>>2, chunk = lane&3
    int pw = (wid - 8) & 3;
    int prow = pw * 16 + (lane >> 2);
    int pch = lane & 3;
    const float* gxp = x + ((size_t)bm * 64 + prow) * INF + pch * 8;
    unsigned awr = (unsigned)(prow * 64 + (((pch ^ ((prow >> 1) & 3)) & 3) * 16));

    f32x4 acc[4][4] = {};
    bf16x8 breg[2][4], afE[4], afO[4];

    // prologue: producers build block 0 -> buf0; consumers preload B(sidx 0)
    if (wid >= 8) { PROD(0, 0); }
    else          { BLD(0, 0); }
    LGKM0();
    BARRIER();

    for (int bb = 0; bb < 16; bb += 2) {
        if (wid < 8) { CBLOCK2(bb, 0, 0); }
        else         { PROD(bb + 1, 28672); }
        LGKM0();
        BARRIER();
        if (wid < 8) { CBLOCK2(bb + 1, 1, 28672); }
        else         { if (bb + 2 < 16) PROD(bb + 2, 0); }
        LGKM0();
        BARRIER();
    }

    // epilogue (consumers only): D row = (lane>>4)*4 + j, col = lane&15
    if (wid < 8) {
        int cr = (lane >> 4) * 4;
        int cc = lane & 15;
        #pragma unroll
        for (int mi = 0; mi < 4; ++mi) {
            #pragma unroll
            for (int ni = 0; ni < 4; ++ni) {
                size_t row = (size_t)bm * 64 + mi * 16 + cr;
                int col = wid * 64 + ni * 16 + cc;
                #pragma unroll
                for (int j = 0; j < 4; ++j)
                    C[(row + j) * OUTF + col] = acc[mi][ni][j];
            }
        }
    }
}

extern "C" void kernel_launch(void* const* d_in, const int* in_sizes, int n_in,
                              void* d_out, int out_size, void* d_ws, size_t ws_size,
                              hipStream_t stream) {
    const float* x  = (const float*)d_in[0];
    const float* bw = (const float*)d_in[1];
    const float* sw = (const float*)d_in[2];
    const float* ss = (const float*)d_in[3];
    float* out = (float*)d_out;
    short* Wbuf = (short*)d_ws;                          // 3.67 MB

    prep_w5<<<(OUTF * 7 * 64 + 255) / 256, 256, 0, stream>>>(bw, sw, ss, Wbuf);
    kan_pc2<<<BATCH / 64, THREADS, 0, stream>>>(x, Wbuf, out);
}